// Round 2
// baseline (379.281 us; speedup 1.0000x reference)
//
#include <hip/hip_runtime.h>
#include <hip/hip_cooperative_groups.h>
#include <cmath>

namespace cg = cooperative_groups;

#define VOCAB   50257
#define HIDDEN  16
#define BATCH   256
#define SEQLEN  8192
#define TCHUNKS 8          // T split for K2 parallelism; chunks merged by atomicAdd
#define K3_BCHUNK 16       // batch rows staged in LDS per K3 unit
#define K3_VPT   4         // vocab columns per thread (component stride 256)

#define FUSED_BLOCKS 1024  // 4 wg/CU x 256 CU co-resident (launch_bounds(256,4))
#define K1_BLOCKS    ((VOCAB + 255) / 256)                          // 197
#define K3_VBLOCKS   ((VOCAB + 256 * K3_VPT - 1) / (256 * K3_VPT))  // 50
#define K3_UNITS     (K3_VBLOCKS * (BATCH / K3_BCHUNK))             // 800

// ---------------------------------------------------------------------------
// int8 table decode helpers. The uitofp((x>>8k)&0xff) pattern is matched by
// the AMDGPU backend to v_cvt_f32_ubyte{0..3} (1 VALU op each).
// ---------------------------------------------------------------------------
__device__ __forceinline__ float ub0(unsigned x){ return (float)( x        & 0xffu); }
__device__ __forceinline__ float ub1(unsigned x){ return (float)((x >> 8 ) & 0xffu); }
__device__ __forceinline__ float ub2(unsigned x){ return (float)((x >> 16) & 0xffu); }
__device__ __forceinline__ float ub3(unsigned x){ return (float)( x >> 24        ); }

// ---------------------------------------------------------------------------
// Phase bodies — shared between the fused cooperative kernel and the
// 3-launch fallback path so both stay semantically identical.
// ---------------------------------------------------------------------------

// K1: per-vocab fused table  c[v][k] = sigmoid(Wg.e+bg) * tanh((Wu^T e)[k]+bu[k])
// int8 fixed-point rows (16 B): q = round(c*127)+128, c in (-1,1) so no clamp.
// Quant err: per-entry std ~2.3e-3 -> sqrt(8192)-accumulated ~0.2/component,
// <=~0.7 on out (budget 28.6, at 8.0). Also zero-inits mem_acc (ws poisoned).
__device__ __forceinline__ void k1_phase(
    int bx, int tid,
    const float* __restrict__ embed, const float* __restrict__ Wg,
    const float* __restrict__ bg,    const float* __restrict__ Wu,
    const float* __restrict__ bu,    unsigned* __restrict__ ctab,
    float* __restrict__ mem_acc, float* sWu, float* sWg, float* sbu)
{
    if (bx < (BATCH * HIDDEN) / 256)              // 16 blocks zero 4096 floats
        mem_acc[bx * 256 + tid] = 0.f;
    if (bx >= K1_BLOCKS) return;                  // block-uniform
    sWu[tid] = Wu[tid];
    if (tid < 16) { sWg[tid] = Wg[tid]; sbu[tid] = bu[tid]; }
    __syncthreads();

    const int v = bx * 256 + tid;
    if (v >= VOCAB) return;

    const float4* er = (const float4*)(embed + (size_t)v * HIDDEN);
    float4 e0 = er[0], e1 = er[1], e2 = er[2], e3 = er[3];
    float e[16] = {e0.x,e0.y,e0.z,e0.w, e1.x,e1.y,e1.z,e1.w,
                   e2.x,e2.y,e2.z,e2.w, e3.x,e3.y,e3.z,e3.w};

    float z = bg[0];
#pragma unroll
    for (int h = 0; h < 16; ++h) z = fmaf(e[h], sWg[h], z);
    const float g = 1.0f / (1.0f + __expf(-z));

    float o[16];
#pragma unroll
    for (int k = 0; k < 16; ++k) {
        float u = sbu[k];
#pragma unroll
        for (int h = 0; h < 16; ++h) u = fmaf(e[h], sWu[h * 16 + k], u);
        // tanh(u) = 1 - 2/(exp(2u)+1) via v_exp_f32; |u| small, no range issue.
        o[k] = g * (1.f - 2.f / (__expf(2.f * u) + 1.f));
    }

    unsigned d[4];
#pragma unroll
    for (int j = 0; j < 4; ++j) {
        unsigned q0 = (unsigned)fmaf(o[4*j+0], 127.f, 128.5f); // trunc = RNE-ish
        unsigned q1 = (unsigned)fmaf(o[4*j+1], 127.f, 128.5f);
        unsigned q2 = (unsigned)fmaf(o[4*j+2], 127.f, 128.5f);
        unsigned q3 = (unsigned)fmaf(o[4*j+3], 127.f, 128.5f);
        d[j] = q0 | (q1 << 8) | (q2 << 16) | (q3 << 24);
    }
    ((uint4*)(ctab + (size_t)v * 4))[0] = make_uint4(d[0], d[1], d[2], d[3]);
}

// K2 unit: mem_acc[b] += sum over one 1024-token chunk of c[seq[b,t]].
// 2-lane-cooperative int8 gather over the L2-resident 804 KB table: lanes
// 2k,2k+1 split one 16 B row into two uint2 loads -> 32 contiguous 16 B
// segments per wave instr. Integer partial sums exact in fp32; offset/scale
// folded into one post-loop FMA per register.
__device__ __forceinline__ void k2_phase(
    int b, int chunk, int tid,
    const int* __restrict__ seq, const unsigned* __restrict__ ctab,
    float* __restrict__ mem_acc, float (*red)[16])
{
    constexpr int TPC = SEQLEN / TCHUNKS;                 // 1024 tokens/chunk
    const int* srow = seq + (size_t)b * SEQLEN + (size_t)chunk * TPC;
    const int sub = tid & 1;                              // which 8 B half of row
    const int tok = tid >> 1;                             // token slot 0..127

    float r[8];
#pragma unroll
    for (int j = 0; j < 8; ++j) r[j] = 0.f;

#pragma unroll
    for (int i = 0; i < TPC / 128; ++i) {                 // 8 iters
        // nontemporal: seq streamed once; don't evict the table from L2
        const int idx = __builtin_nontemporal_load(srow + i * 128 + tok);
        const uint2 p = ((const uint2*)(ctab + (size_t)idx * 4))[sub];
        r[0] += ub0(p.x); r[1] += ub1(p.x); r[2] += ub2(p.x); r[3] += ub3(p.x);
        r[4] += ub0(p.y); r[5] += ub1(p.y); r[6] += ub2(p.y); r[7] += ub3(p.y);
    }

    constexpr float S = 1.f / 127.f;
#pragma unroll
    for (int j = 0; j < 8; ++j)                           // (sum_q - n*128) * S
        r[j] = fmaf(r[j], S, -(float)(TPC / 128) * 128.f * S);

    // reduce over lanes with equal sub (bits 1..5 of lane id)
#pragma unroll
    for (int off = 2; off < 64; off <<= 1)
#pragma unroll
        for (int j = 0; j < 8; ++j) r[j] += __shfl_xor(r[j], off, 64);

    const int lane = tid & 63, wave = tid >> 6;
    if (lane < 2) {                                       // lane == sub here
#pragma unroll
        for (int j = 0; j < 8; ++j) red[wave][lane * 8 + j] = r[j];
    }
    __syncthreads();
    if (tid < 16) {
        atomicAdd(&mem_acc[(size_t)b * HIDDEN + tid],
                  red[0][tid] + red[1][tid] + red[2][tid] + red[3][tid]);
    }
}

// ---------------------------------------------------------------------------
// Fused cooperative kernel: A (table) -> sync -> B (gather) -> sync -> C (out).
// Phase-C's Wo/bo tile (68 VGPRs, 3.2 MB HBM) is loaded BEFORE the first
// sync, so its latency+bytes hide under the gather phase instead of sitting
// serially after it. 1024 blocks = 4 wg/CU; launch_bounds(256,4) caps VGPR
// at 128 so the cooperative-launch occupancy check passes.
// ---------------------------------------------------------------------------
__global__ __launch_bounds__(256, 4) void fused_all(
    const int* __restrict__ seq, const float* __restrict__ embed,
    const float* __restrict__ Wg, const float* __restrict__ bg,
    const float* __restrict__ Wu, const float* __restrict__ bu,
    const float* __restrict__ Wo, const float* __restrict__ bo,
    unsigned* __restrict__ ctab,  float* __restrict__ mem_acc,
    float* __restrict__ out)
{
    __shared__ float sA[256 + 16 + 16];
    __shared__ float red[4][16];
    __shared__ float smem[K3_BCHUNK * 16];

    const int tid = threadIdx.x, bx = blockIdx.x;
    cg::grid_group grid = cg::this_grid();

    // ---- phase A: build table + zero mem_acc (blocks >= 197 idle) ----
    k1_phase(bx, tid, embed, Wg, bg, Wu, bu, ctab, mem_acc,
             sA, sA + 256, sA + 272);

    // ---- phase C prefetch: Wo/bo tile is independent of A and B ----
    const bool cact = bx < K3_UNITS;
    const int vb = cact ? bx % K3_VBLOCKS : 0;
    const int b0 = (cact ? bx / K3_VBLOCKS : 0) * K3_BCHUNK;
    const int vbase = vb * (256 * K3_VPT) + tid;
    bool valid[K3_VPT];
    int  vc[K3_VPT];
    float w[16][K3_VPT], bias[K3_VPT];
    if (cact) {
#pragma unroll
        for (int c = 0; c < K3_VPT; ++c) {
            const int v = vbase + c * 256;
            valid[c] = v < VOCAB;
            vc[c] = valid[c] ? v : 0;
        }
#pragma unroll
        for (int h = 0; h < 16; ++h)
#pragma unroll
            for (int c = 0; c < K3_VPT; ++c)
                w[h][c] = Wo[(size_t)h * VOCAB + vc[c]];  // coalesced scalar
#pragma unroll
        for (int c = 0; c < K3_VPT; ++c) bias[c] = bo[vc[c]];
    }

    grid.sync();

    // ---- phase B: 2048 (b,chunk) units over 1024 blocks, 2 each ----
    for (int u = bx; u < BATCH * TCHUNKS; u += FUSED_BLOCKS) {
        k2_phase(u >> 3, u & 7, tid, seq, ctab, mem_acc, red);
        __syncthreads();                                  // red reused next unit
    }

    grid.sync();

    // ---- phase C: 800 output units, 1 per block (blocks >= 800 idle) ----
    if (cact) {
        smem[tid] = mem_acc[(size_t)b0 * HIDDEN + tid];   // 16 rows x 16 h
        __syncthreads();
#pragma unroll
        for (int bl = 0; bl < K3_BCHUNK; ++bl) {
            float acc[K3_VPT] = {bias[0], bias[1], bias[2], bias[3]};
#pragma unroll
            for (int h = 0; h < 16; ++h) {
                const float mv = smem[bl * 16 + h];       // ds_read_b128-packed
#pragma unroll
                for (int c = 0; c < K3_VPT; ++c)
                    acc[c] = fmaf(mv, w[h][c], acc[c]);
            }
            float* orow = out + (size_t)(b0 + bl) * VOCAB;
#pragma unroll
            for (int c = 0; c < K3_VPT; ++c)
                if (valid[c]) __builtin_nontemporal_store(acc[c], &orow[vc[c]]);
        }
    }
}

// ---------------------------------------------------------------------------
// Fallback path: identical semantics as 3 separate launches (used only if
// hipLaunchCooperativeKernel is rejected, e.g. by graph capture).
// ---------------------------------------------------------------------------
__global__ __launch_bounds__(256) void k1_build_table(
    const float* __restrict__ embed, const float* __restrict__ Wg,
    const float* __restrict__ bg,    const float* __restrict__ Wu,
    const float* __restrict__ bu,    unsigned* __restrict__ ctab,
    float* __restrict__ mem_acc)
{
    __shared__ float sA[256 + 16 + 16];
    k1_phase(blockIdx.x, threadIdx.x, embed, Wg, bg, Wu, bu, ctab, mem_acc,
             sA, sA + 256, sA + 272);
}

__global__ __launch_bounds__(256) void k2_accum(
    const int* __restrict__ seq, const unsigned* __restrict__ ctab,
    float* __restrict__ mem_acc)
{
    __shared__ float red[4][16];
    k2_phase(blockIdx.x, blockIdx.y, threadIdx.x, seq, ctab, mem_acc, red);
}

__global__ __launch_bounds__(256) void k3_output(
    const float* __restrict__ mem_acc, const float* __restrict__ Wo,
    const float* __restrict__ bo,      float* __restrict__ out)
{
    __shared__ float smem[K3_BCHUNK * 16];
    const int tid = threadIdx.x;
    const int b0 = blockIdx.y * K3_BCHUNK;
    smem[tid] = mem_acc[(size_t)b0 * HIDDEN + tid];
    __syncthreads();

    const int vbase = blockIdx.x * (256 * K3_VPT) + tid;
    bool valid[K3_VPT];
    int  vc[K3_VPT];
#pragma unroll
    for (int c = 0; c < K3_VPT; ++c) {
        const int v = vbase + c * 256;
        valid[c] = v < VOCAB;
        vc[c] = valid[c] ? v : 0;
    }

    float w[16][K3_VPT];
#pragma unroll
    for (int h = 0; h < 16; ++h)
#pragma unroll
        for (int c = 0; c < K3_VPT; ++c)
            w[h][c] = Wo[(size_t)h * VOCAB + vc[c]];
    float bias[K3_VPT];
#pragma unroll
    for (int c = 0; c < K3_VPT; ++c) bias[c] = bo[vc[c]];

#pragma unroll
    for (int bl = 0; bl < K3_BCHUNK; ++bl) {
        float acc[K3_VPT] = {bias[0], bias[1], bias[2], bias[3]};
#pragma unroll
        for (int h = 0; h < 16; ++h) {
            const float mv = smem[bl * 16 + h];
#pragma unroll
            for (int c = 0; c < K3_VPT; ++c)
                acc[c] = fmaf(mv, w[h][c], acc[c]);
        }
        float* orow = out + (size_t)(b0 + bl) * VOCAB;
#pragma unroll
        for (int c = 0; c < K3_VPT; ++c)
            if (valid[c]) __builtin_nontemporal_store(acc[c], &orow[vc[c]]);
    }
}

extern "C" void kernel_launch(void* const* d_in, const int* in_sizes, int n_in,
                              void* d_out, int out_size, void* d_ws, size_t ws_size,
                              hipStream_t stream) {
    const int*   seq   = (const int*)  d_in[0];   // [B, T] int32
    const float* embed = (const float*)d_in[1];   // [V, 16]
    const float* Wg    = (const float*)d_in[2];   // [16, 1]
    const float* bg    = (const float*)d_in[3];   // [1]
    const float* Wu    = (const float*)d_in[4];   // [16, 16]
    const float* bu    = (const float*)d_in[5];   // [16]
    const float* Wo    = (const float*)d_in[6];   // [16, V]
    const float* bo    = (const float*)d_in[7];   // [V]
    float* out = (float*)d_out;                   // [B, V] fp32

    unsigned* ctab    = (unsigned*)d_ws;                    // V*4 uint32 (804 KB)
    float*    mem_acc = (float*)(ctab + (size_t)VOCAB * 4); // B*16 floats

    void* kargs[] = {
        (void*)&seq, (void*)&embed, (void*)&Wg, (void*)&bg, (void*)&Wu,
        (void*)&bu, (void*)&Wo, (void*)&bo, (void*)&ctab, (void*)&mem_acc,
        (void*)&out
    };
    hipError_t err = hipLaunchCooperativeKernel(
        (const void*)fused_all, dim3(FUSED_BLOCKS), dim3(256), kargs, 0, stream);
    if (err != hipSuccess) {
        (void)hipGetLastError();                  // clear; use 3-launch fallback
        k1_build_table<<<dim3(K1_BLOCKS), 256, 0, stream>>>(
            embed, Wg, bg, Wu, bu, ctab, mem_acc);
        k2_accum<<<dim3(BATCH, TCHUNKS), 256, 0, stream>>>(seq, ctab, mem_acc);
        k3_output<<<dim3(K3_VBLOCKS, BATCH / K3_BCHUNK), 256, 0, stream>>>(
            mem_acc, Wo, bo, out);
    }
}

// Round 3
// 117.074 us; speedup vs baseline: 3.2397x; 3.2397x over previous
//
#include <hip/hip_runtime.h>
#include <cmath>

#define VOCAB   50257
#define HIDDEN  16
#define BATCH   256
#define SEQLEN  8192
#define TCHUNKS 8          // T split for K2 parallelism; chunks merged by atomicAdd
#define K3_BCHUNK 16       // batch rows staged in LDS per K3 block
#define K3_VPT   4         // vocab columns per thread (component stride 256)

// ---------------------------------------------------------------------------
// int8 table decode helpers. The uitofp((x>>8k)&0xff) pattern is matched by
// the AMDGPU backend to v_cvt_f32_ubyte{0..3} (1 VALU op each).
// ---------------------------------------------------------------------------
__device__ __forceinline__ float ub0(unsigned x){ return (float)( x        & 0xffu); }
__device__ __forceinline__ float ub1(unsigned x){ return (float)((x >> 8 ) & 0xffu); }
__device__ __forceinline__ float ub2(unsigned x){ return (float)((x >> 16) & 0xffu); }
__device__ __forceinline__ float ub3(unsigned x){ return (float)( x >> 24        ); }

// ---------------------------------------------------------------------------
// K1: per-vocab fused table  c[v][k] = sigmoid(Wg.e+bg) * tanh((Wu^T e)[k]+bu[k])
// Stored as int8 fixed-point:  q = round(c*127) + 128  (c strictly in (-1,1)
// so q in [1,255], no clamp needed).  Row = 16 B (uint4) — halves K2's L2
// gather bytes vs bf16.  Quantization step 1/127: per-entry err std ~2.3e-3,
// sqrt(8192)-accumulated ~0.2 per memory[b][k], <=~0.7 added to out absmax
// (budget 28.6, measured 8.0 — unchanged from bf16 version).
// Also zero-inits the 256x16 memory accumulator (ws is poisoned 0xAA).
//
// [R2 NOTE] Do NOT re-fuse these kernels with cg::grid_group::sync():
// measured 285 µs/dispatch at 3% HBM / 3% VALU — grid.sync across 1024
// blocks/8 XCDs costs ~100x more than the graph-node boundaries it removes.
// ---------------------------------------------------------------------------
__global__ __launch_bounds__(256) void k1_build_table(
    const float* __restrict__ embed, const float* __restrict__ Wg,
    const float* __restrict__ bg,    const float* __restrict__ Wu,
    const float* __restrict__ bu,    unsigned* __restrict__ ctab,
    float* __restrict__ mem_acc)
{
    __shared__ float sWu[256], sWg[16], sbu[16];
    const int tid = threadIdx.x;
    sWu[tid] = Wu[tid];
    if (tid < 16) { sWg[tid] = Wg[tid]; sbu[tid] = bu[tid]; }
    if (blockIdx.x < (BATCH * HIDDEN) / 256)              // 16 blocks zero 4096 floats
        mem_acc[blockIdx.x * 256 + tid] = 0.f;
    __syncthreads();

    const int v = blockIdx.x * 256 + tid;
    if (v >= VOCAB) return;

    const float4* er = (const float4*)(embed + (size_t)v * HIDDEN);
    float4 e0 = er[0], e1 = er[1], e2 = er[2], e3 = er[3];
    float e[16] = {e0.x,e0.y,e0.z,e0.w, e1.x,e1.y,e1.z,e1.w,
                   e2.x,e2.y,e2.z,e2.w, e3.x,e3.y,e3.z,e3.w};

    float z = bg[0];
#pragma unroll
    for (int h = 0; h < 16; ++h) z = fmaf(e[h], sWg[h], z);
    const float g = 1.0f / (1.0f + __expf(-z));

    float o[16];
#pragma unroll
    for (int k = 0; k < 16; ++k) {
        float u = sbu[k];
#pragma unroll
        for (int h = 0; h < 16; ++h) u = fmaf(e[h], sWu[h * 16 + k], u);
        // tanh(u) = 1 - 2/(exp(2u)+1): ~5 ops via v_exp_f32 vs slow libm tanhf.
        // |u| <= ~0.6 here (embed*0.02, Wu in +-1/4), well inside __expf range.
        o[k] = g * (1.f - 2.f / (__expf(2.f * u) + 1.f));
    }

    unsigned d[4];
#pragma unroll
    for (int j = 0; j < 4; ++j) {
        unsigned q0 = (unsigned)fmaf(o[4*j+0], 127.f, 128.5f); // trunc = round-half-up
        unsigned q1 = (unsigned)fmaf(o[4*j+1], 127.f, 128.5f);
        unsigned q2 = (unsigned)fmaf(o[4*j+2], 127.f, 128.5f);
        unsigned q3 = (unsigned)fmaf(o[4*j+3], 127.f, 128.5f);
        d[j] = q0 | (q1 << 8) | (q2 << 16) | (q3 << 24);
    }
    ((uint4*)(ctab + (size_t)v * 4))[0] = make_uint4(d[0], d[1], d[2], d[3]);
}

// ---------------------------------------------------------------------------
// K2: mem_acc[b] += sum_t c[seq[b,t]] — int8 gather-sum over the L2-resident
// 804 KB table. 2-lane-cooperative: lanes 2k,2k+1 split one 16 B row into two
// uint2 (8 B) loads -> 32 contiguous 16 B segments per wave instr. Decode is
// v_cvt_f32_ubyte + v_add (16 VALU/token). Integer partial sums are exact in
// fp32 (<= 8*255); offset/scale folded into ONE post-loop FMA per register:
// (sum_q - 8*128) * (1/127).
// ---------------------------------------------------------------------------
__global__ __launch_bounds__(256) void k2_accum(
    const int* __restrict__ seq, const unsigned* __restrict__ ctab,
    float* __restrict__ mem_acc)
{
    const int b = blockIdx.x, chunk = blockIdx.y, tid = threadIdx.x;
    constexpr int TPC = SEQLEN / TCHUNKS;                 // 1024 tokens/chunk
    const int* srow = seq + (size_t)b * SEQLEN + (size_t)chunk * TPC;
    const int sub = tid & 1;                              // which 8 B half of row
    const int tok = tid >> 1;                             // token slot 0..127

    float r[8];
#pragma unroll
    for (int j = 0; j < 8; ++j) r[j] = 0.f;

#pragma unroll
    for (int i = 0; i < TPC / 128; ++i) {                 // 8 iters
        // nontemporal: seq is streamed once; don't evict the table from L2
        const int idx = __builtin_nontemporal_load(srow + i * 128 + tok);
        const uint2 p = ((const uint2*)(ctab + (size_t)idx * 4))[sub];
        r[0] += ub0(p.x); r[1] += ub1(p.x); r[2] += ub2(p.x); r[3] += ub3(p.x);
        r[4] += ub0(p.y); r[5] += ub1(p.y); r[6] += ub2(p.y); r[7] += ub3(p.y);
    }

    constexpr float S = 1.f / 127.f;
#pragma unroll
    for (int j = 0; j < 8; ++j)                           // (sum_q - n*128) * S
        r[j] = fmaf(r[j], S, -(float)(TPC / 128) * 128.f * S);

    // reduce over lanes with equal sub (bits 1..5 of lane id)
#pragma unroll
    for (int off = 2; off < 64; off <<= 1)
#pragma unroll
        for (int j = 0; j < 8; ++j) r[j] += __shfl_xor(r[j], off, 64);

    __shared__ float red[4][16];
    const int lane = tid & 63, wave = tid >> 6;
    if (lane < 2) {                                       // lane == sub here
#pragma unroll
        for (int j = 0; j < 8; ++j) red[wave][lane * 8 + j] = r[j];
    }
    __syncthreads();
    if (tid < 16) {
        atomicAdd(&mem_acc[(size_t)b * HIDDEN + tid],
                  red[0][tid] + red[1][tid] + red[2][tid] + red[3][tid]);
    }
}

// ---------------------------------------------------------------------------
// K3: out[b][v] = memory[b] . Wo[:,v] + bo[v]  — write-BW bound (51.5 MB).
// LDS-staged memory rows + 4 vocab columns per thread (component stride 256
// keeps every global access a fully-coalesced scalar load/store — VOCAB is
// odd so float4 on Wo rows would be misaligned). Nontemporal stores: out is
// never re-read, keep it out of L2.  [R6: 124.6 -> 115.9 µs]
// ---------------------------------------------------------------------------
__global__ __launch_bounds__(256) void k3_output(
    const float* __restrict__ mem_acc, const float* __restrict__ Wo,
    const float* __restrict__ bo,      float* __restrict__ out)
{
    __shared__ float smem[K3_BCHUNK * 16];                // 16 rows x 16 h
    const int tid = threadIdx.x;
    const int b0 = blockIdx.y * K3_BCHUNK;
    smem[tid] = mem_acc[(size_t)b0 * HIDDEN + tid];       // 256 floats, coalesced
    __syncthreads();

    const int vbase = blockIdx.x * (256 * K3_VPT) + tid;  // component c at +256c
    bool valid[K3_VPT];
    int  vc[K3_VPT];
#pragma unroll
    for (int c = 0; c < K3_VPT; ++c) {
        const int v = vbase + c * 256;
        valid[c] = v < VOCAB;
        vc[c] = valid[c] ? v : 0;
    }

    float w[16][K3_VPT];
#pragma unroll
    for (int h = 0; h < 16; ++h)
#pragma unroll
        for (int c = 0; c < K3_VPT; ++c)
            w[h][c] = Wo[(size_t)h * VOCAB + vc[c]];      // coalesced scalar
    float bias[K3_VPT];
#pragma unroll
    for (int c = 0; c < K3_VPT; ++c) bias[c] = bo[vc[c]];

#pragma unroll
    for (int bl = 0; bl < K3_BCHUNK; ++bl) {
        float acc[K3_VPT] = {bias[0], bias[1], bias[2], bias[3]};
#pragma unroll
        for (int h = 0; h < 16; ++h) {
            const float mv = smem[bl * 16 + h];           // ds_read_b128-packed
#pragma unroll
            for (int c = 0; c < K3_VPT; ++c)
                acc[c] = fmaf(mv, w[h][c], acc[c]);
        }
        float* orow = out + (size_t)(b0 + bl) * VOCAB;
#pragma unroll
        for (int c = 0; c < K3_VPT; ++c)
            if (valid[c]) __builtin_nontemporal_store(acc[c], &orow[vc[c]]);
    }
}

extern "C" void kernel_launch(void* const* d_in, const int* in_sizes, int n_in,
                              void* d_out, int out_size, void* d_ws, size_t ws_size,
                              hipStream_t stream) {
    const int*   seq   = (const int*)  d_in[0];   // [B, T] int32
    const float* embed = (const float*)d_in[1];   // [V, 16]
    const float* Wg    = (const float*)d_in[2];   // [16, 1]
    const float* bg    = (const float*)d_in[3];   // [1]
    const float* Wu    = (const float*)d_in[4];   // [16, 16]
    const float* bu    = (const float*)d_in[5];   // [16]
    const float* Wo    = (const float*)d_in[6];   // [16, V]
    const float* bo    = (const float*)d_in[7];   // [V]
    float* out = (float*)d_out;                   // [B, V] fp32

    unsigned* ctab    = (unsigned*)d_ws;                    // V*4 uint32 (804 KB, int8 rows)
    float*    mem_acc = (float*)(ctab + (size_t)VOCAB * 4); // B*16 floats

    k1_build_table<<<dim3((VOCAB + 255) / 256), 256, 0, stream>>>(
        embed, Wg, bg, Wu, bu, ctab, mem_acc);
    k2_accum<<<dim3(BATCH, TCHUNKS), 256, 0, stream>>>(seq, ctab, mem_acc);
    k3_output<<<dim3((VOCAB + 256 * K3_VPT - 1) / (256 * K3_VPT),
                     BATCH / K3_BCHUNK), 256, 0, stream>>>(
        mem_acc, Wo, bo, out);
}